// Round 4
// baseline (1080.758 us; speedup 1.0000x reference)
//
#include <hip/hip_runtime.h>
#include <hip/hip_bf16.h>

#define NNODES 100000
#define NEDGES 1600000
#define NRELS 16
#define NBASES 8
#define DFEAT 128
#define NCLS 40
#define MAXDEG 64
#define KTOT 1152   // NBASES*128 + 128 (root)

typedef __attribute__((ext_vector_type(8))) short bf16x8v;
typedef __attribute__((ext_vector_type(4))) float f32x4v;
typedef __attribute__((ext_vector_type(2))) float f32x2v;

__global__ __launch_bounds__(256)
void k_convert(const float* __restrict__ x, __hip_bfloat16* __restrict__ xb, int n)
{
    int i = blockIdx.x * 256 + threadIdx.x;
    if (i < n) xb[i] = __float2bfloat16(x[i]);
}

// One atomic per edge: degD slot-claim doubles as ELL write index.
__global__ __launch_bounds__(256)
void k_build(const int* __restrict__ esrc, const int* __restrict__ edst,
             const int* __restrict__ etyp,
             unsigned* __restrict__ degD, unsigned* __restrict__ ell)
{
    int e = blockIdx.x * 256 + threadIdx.x;
    if (e >= NEDGES) return;
    int d = edst[e], t = etyp[e], s = esrc[e];
    unsigned slot = atomicAdd(&degD[d], 1u);
    if (slot < MAXDEG) ell[(size_t)d * MAXDEG + slot] = ((unsigned)s << 4) | (unsigned)t;
}

// Per-row int8 quantization of node features (neighbor gather path).
__global__ __launch_bounds__(256)
void k_quant(const __hip_bfloat16* __restrict__ h,
             short* __restrict__ q8, float* __restrict__ qs, int nrows)
{
    int wave = threadIdx.x >> 6, lane = threadIdx.x & 63;
    int v = blockIdx.x * 4 + wave;
    if (v >= nrows) return;
    __hip_bfloat162 xv = ((const __hip_bfloat162*)h)[(size_t)v * 64 + lane];
    float xl = __bfloat162float(xv.x), xh = __bfloat162float(xv.y);
    float m = fmaxf(fabsf(xl), fabsf(xh));
#pragma unroll
    for (int o = 32; o; o >>= 1) m = fmaxf(m, __shfl_xor(m, o));
    float inv = (m > 0.f) ? 127.f / m : 0.f;
    int qx = (int)rintf(xl * inv), qy = (int)rintf(xh * inv);
    q8[(size_t)v * 64 + lane] = (short)((qx & 0xff) | (qy << 8));
    if (lane == 0) qs[v] = m * (1.f / 127.f);
}

// One wave per node. Lane e owns edge e: it precomputes the fully-folded
// coefficient vector c_l[b] = comp[t_e,b] * (1/deg(dst,t_e)) * qs[src_e]
// ONCE (8 LDS reads per node, zero in the edge loop). The edge loop
// broadcasts c via __shfl with wave-uniform index -> v_readlane (SGPR),
// and accumulates with packed float2 FMAs (v_pk_fma_f32).
__global__ __launch_bounds__(256)
void k_agg(const short* __restrict__ q8, const float* __restrict__ qs,
           const __hip_bfloat16* __restrict__ hin,
           const unsigned* __restrict__ ell,
           const unsigned* __restrict__ degD,
           const float* __restrict__ comp,
           __hip_bfloat16* __restrict__ A,
           int r0, int rows)
{
    __shared__ float compS[NRELS * NBASES];
    if (threadIdx.x < NRELS * NBASES) compS[threadIdx.x] = comp[threadIdx.x];
    __syncthreads();
    int wave = threadIdx.x >> 6, lane = threadIdx.x & 63;
    int rl = blockIdx.x * 4 + wave;
    if (rl >= rows) return;
    int v = r0 + rl;
    int ne = (int)degD[v]; if (ne > MAXDEG) ne = MAXDEG;
    const unsigned* erow = ell + (size_t)v * MAXDEG;
    unsigned packed = (lane < ne) ? erow[lane] : 0u;
    unsigned t_l = packed & 15u;
    int s_l = (int)(packed >> 4);
    unsigned long long m = __ballot(lane < ne);
#pragma unroll
    for (int b = 0; b < 4; b++) {
        unsigned long long bb = __ballot((t_l >> b) & 1u);
        m &= ((t_l >> b) & 1u) ? bb : ~bb;
    }
    int cnt = __popcll(m); if (cnt < 1) cnt = 1;
    // folded per-edge weight; 0 for inactive lanes -> branchless padded batches
    float w_l = (lane < ne) ? (qs[s_l] / (float)cnt) : 0.f;
    float c_l[NBASES];
#pragma unroll
    for (int b = 0; b < NBASES; b++) c_l[b] = compS[t_l * NBASES + b] * w_l;

    f32x2v acc[NBASES];
#pragma unroll
    for (int b = 0; b < NBASES; b++) acc[b] = (f32x2v){0.f, 0.f};

    for (int e0 = 0; e0 < ne; e0 += 8) {
        short qv[8];
#pragma unroll
        for (int j = 0; j < 8; j++) {          // issue 8 gathers, stay in flight
            unsigned ed = __shfl(packed, e0 + j);
            qv[j] = q8[(size_t)(ed >> 4) * 64 + lane];
        }
#pragma unroll
        for (int j = 0; j < 8; j++) {
            f32x2v f2;
            f2.x = (float)(char)qv[j];
            f2.y = (float)(qv[j] >> 8);
#pragma unroll
            for (int b = 0; b < NBASES; b++) {
                float cb = __shfl(c_l[b], e0 + j);   // readlane -> SGPR
                acc[b] += cb * f2;                    // v_pk_fma_f32
            }
        }
    }
    const __hip_bfloat162* h2p = (const __hip_bfloat162*)hin;
    __hip_bfloat162* A2 = (__hip_bfloat162*)(A + (size_t)rl * KTOT);
#pragma unroll
    for (int b = 0; b < NBASES; b++) {
        __hip_bfloat162 o;
        o.x = __float2bfloat16(acc[b].x);
        o.y = __float2bfloat16(acc[b].y);
        A2[b * 64 + lane] = o;
    }
    A2[512 + lane] = h2p[(size_t)v * 64 + lane];   // root part: own features (bf16)
}

// WT[o][k] (B^T, K-contiguous).
__global__ __launch_bounds__(256)
void k_w(const float* __restrict__ bases, const float* __restrict__ root,
         __hip_bfloat16* __restrict__ WT, int dout, int npad)
{
    int idx = blockIdx.x * 256 + threadIdx.x;
    int total = npad * KTOT;
    if (idx >= total) return;
    int o = idx / KTOT, k = idx - o * KTOT;
    float v = 0.f;
    if (o < dout) v = (k < 1024) ? bases[k * dout + o] : root[(k - 1024) * dout + o];
    WT[idx] = __float2bfloat16(v);
}

// C[M,NT] = A[M,K] * WT[NT,K]^T. 128x{128|64} tile, BK=32, 4 waves,
// mfma_f32_16x16x32_bf16, global_load_lds (width 16) staging.
template<int NT, bool RELU, bool FINAL>
__global__ __launch_bounds__(256)
void k_gemm(const __hip_bfloat16* __restrict__ A,
            const __hip_bfloat16* __restrict__ WT,
            const float* __restrict__ bias,
            void* __restrict__ outp,
            int r0, int rows, int dout)
{
    constexpr int WM = (NT == 128) ? 2 : 4;
    constexpr int WN = 4 / WM;
    constexpr int MT = 128 / (16 * WM);
    constexpr int NTW = NT / (16 * WN);
    __shared__ __align__(16) __hip_bfloat16 As[128 * 32];
    __shared__ __align__(16) __hip_bfloat16 Bs[NT * 32];
    int tid = threadIdx.x;
    int wave = tid >> 6, lane = tid & 63;
    int wm = wave % WM, wn = wave / WM;
    int bm = blockIdx.x * 128;
    int lm = lane & 15, lq = lane >> 4;
    f32x4v zero = {0.f, 0.f, 0.f, 0.f};
    f32x4v acc[MT][NTW];
#pragma unroll
    for (int a = 0; a < MT; a++)
#pragma unroll
        for (int b = 0; b < NTW; b++) acc[a][b] = zero;

    for (int k0 = 0; k0 < KTOT; k0 += 32) {
#pragma unroll
        for (int j = 0; j < 2; j++) {
            int slot = tid + 256 * j;
            int row = slot >> 2, kc = (slot & 3) << 3;
            __builtin_amdgcn_global_load_lds(
                (const __attribute__((address_space(1))) void*)
                    &A[(size_t)(bm + row) * KTOT + k0 + kc],
                (__attribute__((address_space(3))) void*)&As[slot * 8],
                16, 0, 0);
        }
#pragma unroll
        for (int j = 0; j < NT / 64; j++) {
            int slot = tid + 256 * j;
            int row = slot >> 2, kc = (slot & 3) << 3;
            __builtin_amdgcn_global_load_lds(
                (const __attribute__((address_space(1))) void*)
                    &WT[(size_t)row * KTOT + k0 + kc],
                (__attribute__((address_space(3))) void*)&Bs[slot * 8],
                16, 0, 0);
        }
        __syncthreads();
        bf16x8v af[MT], bfr[NTW];
#pragma unroll
        for (int mt = 0; mt < MT; mt++)
            af[mt] = *(const bf16x8v*)&As[(wm * (16 * MT) + mt * 16 + lm) * 32 + lq * 8];
#pragma unroll
        for (int nt = 0; nt < NTW; nt++)
            bfr[nt] = *(const bf16x8v*)&Bs[(wn * (16 * NTW) + nt * 16 + lm) * 32 + lq * 8];
#pragma unroll
        for (int mt = 0; mt < MT; mt++)
#pragma unroll
            for (int nt = 0; nt < NTW; nt++)
                acc[mt][nt] = __builtin_amdgcn_mfma_f32_16x16x32_bf16(
                    af[mt], bfr[nt], acc[mt][nt], 0, 0, 0);
        __syncthreads();
    }
#pragma unroll
    for (int mt = 0; mt < MT; mt++) {
        int rbase = bm + wm * (16 * MT) + mt * 16 + lq * 4;
#pragma unroll
        for (int nt = 0; nt < NTW; nt++) {
            int col = wn * (16 * NTW) + nt * 16 + lm;
#pragma unroll
            for (int i = 0; i < 4; i++) {
                int rl = rbase + i;
                if (rl < rows && col < dout) {
                    float v = acc[mt][nt][i] + bias[col];
                    if (RELU) v = fmaxf(v, 0.f);
                    if (FINAL)
                        ((float*)outp)[(size_t)(r0 + rl) * NCLS + col] = v;
                    else
                        ((__hip_bfloat16*)outp)[(size_t)(r0 + rl) * DFEAT + col] =
                            __float2bfloat16(v);
                }
            }
        }
    }
}

extern "C" void kernel_launch(void* const* d_in, const int* in_sizes, int n_in,
                              void* d_out, int out_size, void* d_ws, size_t ws_size,
                              hipStream_t stream)
{
    const float* x  = (const float*)d_in[0];
    const int* esrc = (const int*)d_in[1];
    const int* edst = (const int*)d_in[2];
    const int* etyp = (const int*)d_in[3];
    const float* basesA[3] = {(const float*)d_in[4], (const float*)d_in[8], (const float*)d_in[12]};
    const float* compA[3]  = {(const float*)d_in[5], (const float*)d_in[9], (const float*)d_in[13]};
    const float* rootA[3]  = {(const float*)d_in[6], (const float*)d_in[10], (const float*)d_in[14]};
    const float* biasA[3]  = {(const float*)d_in[7], (const float*)d_in[11], (const float*)d_in[15]};

    size_t off = 0;
    char* base = (char*)d_ws;
    auto carve = [&](size_t bytes) -> void* {
        void* r = base + off;
        off += (bytes + 255) & ~(size_t)255;
        return r;
    };
    __hip_bfloat16* xb = (__hip_bfloat16*)carve((size_t)NNODES * DFEAT * 2);
    __hip_bfloat16* h1 = (__hip_bfloat16*)carve((size_t)NNODES * DFEAT * 2);
    __hip_bfloat16* WT = (__hip_bfloat16*)carve((size_t)128 * KTOT * 2);
    unsigned* ell  = (unsigned*)carve((size_t)NNODES * MAXDEG * 4);
    unsigned* degD = (unsigned*)carve((size_t)NNODES * 4);
    short* q8  = (short*)carve((size_t)NNODES * 64 * 2);
    float* qsc = (float*)carve((size_t)NNODES * 4);
    __hip_bfloat16* h2 = xb;   // xb dead after layer 1 -> alias

    if (ws_size <= off) return;
    size_t arows = (ws_size - off) / ((size_t)KTOT * 2);
    if (arows > 100096) arows = 100096;
    int chunk = (int)(arows & ~(size_t)127);
    if (chunk < 128) return;
    __hip_bfloat16* A = (__hip_bfloat16*)(base + off);

    hipMemsetAsync(degD, 0, (size_t)NNODES * 4, stream);
    k_convert<<<(NNODES * DFEAT + 255) / 256, 256, 0, stream>>>(x, xb, NNODES * DFEAT);
    k_build<<<(NEDGES + 255) / 256, 256, 0, stream>>>(esrc, edst, etyp, degD, ell);

    const __hip_bfloat16* hin = xb;
    __hip_bfloat16* houts[2] = {h1, h2};
    for (int l = 0; l < 3; l++) {
        int dout = (l == 2) ? NCLS : DFEAT;
        int npad = (l == 2) ? 64 : 128;
        k_quant<<<(NNODES + 3) / 4, 256, 0, stream>>>(hin, q8, qsc, NNODES);
        k_w<<<(npad * KTOT + 255) / 256, 256, 0, stream>>>(basesA[l], rootA[l], WT, dout, npad);
        for (int r0 = 0; r0 < NNODES; r0 += chunk) {
            int rows = NNODES - r0; if (rows > chunk) rows = chunk;
            k_agg<<<(rows + 3) / 4, 256, 0, stream>>>(q8, qsc, hin, ell, degD, compA[l], A, r0, rows);
            int gm = (rows + 127) / 128;
            if (l < 2)
                k_gemm<128, true, false><<<gm, 256, 0, stream>>>(A, WT, biasA[l], houts[l], r0, rows, dout);
            else
                k_gemm<64, false, true><<<gm, 256, 0, stream>>>(A, WT, biasA[l], d_out, r0, rows, dout);
        }
        if (l < 2) hin = houts[l];
    }
}

// Round 5
// 832.041 us; speedup vs baseline: 1.2989x; 1.2989x over previous
//
#include <hip/hip_runtime.h>
#include <hip/hip_bf16.h>

#define NNODES 100000
#define NEDGES 1600000
#define NRELS 16
#define NBASES 8
#define DFEAT 128
#define NCLS 40
#define MAXDEG 64
#define KTOT 1152   // NBASES*128 + 128 (root)

typedef __attribute__((ext_vector_type(8))) short bf16x8v;
typedef __attribute__((ext_vector_type(4))) float f32x4v;
typedef __attribute__((ext_vector_type(2))) float f32x2v;

__global__ __launch_bounds__(256)
void k_convert(const float* __restrict__ x, __hip_bfloat16* __restrict__ xb, int n)
{
    int i = blockIdx.x * 256 + threadIdx.x;
    if (i < n) xb[i] = __float2bfloat16(x[i]);
}

// One atomic per edge: degD slot-claim doubles as ELL write index.
__global__ __launch_bounds__(256)
void k_build(const int* __restrict__ esrc, const int* __restrict__ edst,
             const int* __restrict__ etyp,
             unsigned* __restrict__ degD, unsigned* __restrict__ ell)
{
    int e = blockIdx.x * 256 + threadIdx.x;
    if (e >= NEDGES) return;
    int d = edst[e], t = etyp[e], s = esrc[e];
    unsigned slot = atomicAdd(&degD[d], 1u);
    if (slot < MAXDEG) ell[(size_t)d * MAXDEG + slot] = ((unsigned)s << 4) | (unsigned)t;
}

// Per-row int8 quantization of node features (neighbor gather path).
__global__ __launch_bounds__(256)
void k_quant(const __hip_bfloat16* __restrict__ h,
             short* __restrict__ q8, float* __restrict__ qs, int nrows)
{
    int wave = threadIdx.x >> 6, lane = threadIdx.x & 63;
    int v = blockIdx.x * 4 + wave;
    if (v >= nrows) return;
    __hip_bfloat162 xv = ((const __hip_bfloat162*)h)[(size_t)v * 64 + lane];
    float xl = __bfloat162float(xv.x), xh = __bfloat162float(xv.y);
    float m = fmaxf(fabsf(xl), fabsf(xh));
#pragma unroll
    for (int o = 32; o; o >>= 1) m = fmaxf(m, __shfl_xor(m, o));
    float inv = (m > 0.f) ? 127.f / m : 0.f;
    int qx = (int)rintf(xl * inv), qy = (int)rintf(xh * inv);
    q8[(size_t)v * 64 + lane] = (short)((qx & 0xff) | (qy << 8));
    if (lane == 0) qs[v] = m * (1.f / 127.f);
}

// One wave per node. Lane e owns edge e: folded coefficients
// c[b] = comp[t_e,b] * (1/deg(dst,t_e)) * qs[src_e] and src index are
// written to LDS ONCE per node; the edge loop reads them back at
// wave-uniform addresses (ds_read_b128 broadcast = conflict-free, no
// bpermute!). Packed f32x2 accumulation -> v_pk_fma_f32.
__global__ __launch_bounds__(256)
void k_agg(const short* __restrict__ q8, const float* __restrict__ qs,
           const __hip_bfloat16* __restrict__ hin,
           const unsigned* __restrict__ ell,
           const unsigned* __restrict__ degD,
           const float* __restrict__ comp,
           __hip_bfloat16* __restrict__ A,
           int r0, int rows)
{
    __shared__ float compS[NRELS * NBASES];
    __shared__ __align__(16) float cS[4][MAXDEG][8];
    __shared__ unsigned sS[4][MAXDEG];
    if (threadIdx.x < NRELS * NBASES) compS[threadIdx.x] = comp[threadIdx.x];
    __syncthreads();
    int wave = threadIdx.x >> 6, lane = threadIdx.x & 63;
    int rl = blockIdx.x * 4 + wave;
    if (rl >= rows) return;
    int v = r0 + rl;
    int ne = (int)degD[v]; if (ne > MAXDEG) ne = MAXDEG;
    const unsigned* erow = ell + (size_t)v * MAXDEG;
    unsigned packed = (lane < ne) ? erow[lane] : 0u;
    unsigned t_l = packed & 15u;
    int s_l = (lane < ne) ? (int)(packed >> 4) : 0;
    unsigned long long m = __ballot(lane < ne);
#pragma unroll
    for (int b = 0; b < 4; b++) {
        unsigned long long bb = __ballot((t_l >> b) & 1u);
        m &= ((t_l >> b) & 1u) ? bb : ~bb;
    }
    int cnt = __popcll(m); if (cnt < 1) cnt = 1;
    float w_l = (lane < ne) ? (qs[s_l] / (float)cnt) : 0.f;   // 0 => branchless pad
    f32x4v c0, c1;
#pragma unroll
    for (int b = 0; b < 4; b++) c0[b] = compS[t_l * NBASES + b] * w_l;
#pragma unroll
    for (int b = 0; b < 4; b++) c1[b] = compS[t_l * NBASES + 4 + b] * w_l;
    *(f32x4v*)&cS[wave][lane][0] = c0;          // once per node
    *(f32x4v*)&cS[wave][lane][4] = c1;
    sS[wave][lane] = (unsigned)s_l;
    // same-wave RAW on LDS: compiler's lgkmcnt ordering suffices, no barrier

    f32x2v acc[NBASES];
#pragma unroll
    for (int b = 0; b < NBASES; b++) acc[b] = (f32x2v){0.f, 0.f};

    for (int e0 = 0; e0 < ne; e0 += 8) {
        unsigned sj[8]; short qv[8];
#pragma unroll
        for (int j = 0; j < 8; j++) sj[j] = sS[wave][e0 + j];   // uniform -> broadcast
#pragma unroll
        for (int j = 0; j < 8; j++)                              // 8 gathers in flight
            qv[j] = q8[(size_t)sj[j] * 64 + lane];
#pragma unroll
        for (int j = 0; j < 8; j++) {
            f32x4v ca = *(const f32x4v*)&cS[wave][e0 + j][0];    // uniform b128 broadcast
            f32x4v cb = *(const f32x4v*)&cS[wave][e0 + j][4];
            f32x2v f2;
            f2.x = (float)(char)(qv[j] & 0xff);
            f2.y = (float)(qv[j] >> 8);
            acc[0] += ca[0] * f2;  acc[1] += ca[1] * f2;
            acc[2] += ca[2] * f2;  acc[3] += ca[3] * f2;
            acc[4] += cb[0] * f2;  acc[5] += cb[1] * f2;
            acc[6] += cb[2] * f2;  acc[7] += cb[3] * f2;
        }
    }
    const __hip_bfloat162* h2p = (const __hip_bfloat162*)hin;
    __hip_bfloat162* A2 = (__hip_bfloat162*)(A + (size_t)rl * KTOT);
#pragma unroll
    for (int b = 0; b < NBASES; b++) {
        __hip_bfloat162 o;
        o.x = __float2bfloat16(acc[b].x);
        o.y = __float2bfloat16(acc[b].y);
        A2[b * 64 + lane] = o;
    }
    A2[512 + lane] = h2p[(size_t)v * 64 + lane];   // root part: own features (bf16)
}

// WT[o][k] (B^T, K-contiguous).
__global__ __launch_bounds__(256)
void k_w(const float* __restrict__ bases, const float* __restrict__ root,
         __hip_bfloat16* __restrict__ WT, int dout, int npad)
{
    int idx = blockIdx.x * 256 + threadIdx.x;
    int total = npad * KTOT;
    if (idx >= total) return;
    int o = idx / KTOT, k = idx - o * KTOT;
    float v = 0.f;
    if (o < dout) v = (k < 1024) ? bases[k * dout + o] : root[(k - 1024) * dout + o];
    WT[idx] = __float2bfloat16(v);
}

// C[M,NT] = A[M,K] * WT[NT,K]^T. 128x{128|64} tile, BK=32, 4 waves,
// mfma_f32_16x16x32_bf16, global_load_lds (width 16) staging.
template<int NT, bool RELU, bool FINAL>
__global__ __launch_bounds__(256)
void k_gemm(const __hip_bfloat16* __restrict__ A,
            const __hip_bfloat16* __restrict__ WT,
            const float* __restrict__ bias,
            void* __restrict__ outp,
            int r0, int rows, int dout)
{
    constexpr int WM = (NT == 128) ? 2 : 4;
    constexpr int WN = 4 / WM;
    constexpr int MT = 128 / (16 * WM);
    constexpr int NTW = NT / (16 * WN);
    __shared__ __align__(16) __hip_bfloat16 As[128 * 32];
    __shared__ __align__(16) __hip_bfloat16 Bs[NT * 32];
    int tid = threadIdx.x;
    int wave = tid >> 6, lane = tid & 63;
    int wm = wave % WM, wn = wave / WM;
    int bm = blockIdx.x * 128;
    int lm = lane & 15, lq = lane >> 4;
    f32x4v zero = {0.f, 0.f, 0.f, 0.f};
    f32x4v acc[MT][NTW];
#pragma unroll
    for (int a = 0; a < MT; a++)
#pragma unroll
        for (int b = 0; b < NTW; b++) acc[a][b] = zero;

    for (int k0 = 0; k0 < KTOT; k0 += 32) {
#pragma unroll
        for (int j = 0; j < 2; j++) {
            int slot = tid + 256 * j;
            int row = slot >> 2, kc = (slot & 3) << 3;
            __builtin_amdgcn_global_load_lds(
                (const __attribute__((address_space(1))) void*)
                    &A[(size_t)(bm + row) * KTOT + k0 + kc],
                (__attribute__((address_space(3))) void*)&As[slot * 8],
                16, 0, 0);
        }
#pragma unroll
        for (int j = 0; j < NT / 64; j++) {
            int slot = tid + 256 * j;
            int row = slot >> 2, kc = (slot & 3) << 3;
            __builtin_amdgcn_global_load_lds(
                (const __attribute__((address_space(1))) void*)
                    &WT[(size_t)row * KTOT + k0 + kc],
                (__attribute__((address_space(3))) void*)&Bs[slot * 8],
                16, 0, 0);
        }
        __syncthreads();
        bf16x8v af[MT], bfr[NTW];
#pragma unroll
        for (int mt = 0; mt < MT; mt++)
            af[mt] = *(const bf16x8v*)&As[(wm * (16 * MT) + mt * 16 + lm) * 32 + lq * 8];
#pragma unroll
        for (int nt = 0; nt < NTW; nt++)
            bfr[nt] = *(const bf16x8v*)&Bs[(wn * (16 * NTW) + nt * 16 + lm) * 32 + lq * 8];
#pragma unroll
        for (int mt = 0; mt < MT; mt++)
#pragma unroll
            for (int nt = 0; nt < NTW; nt++)
                acc[mt][nt] = __builtin_amdgcn_mfma_f32_16x16x32_bf16(
                    af[mt], bfr[nt], acc[mt][nt], 0, 0, 0);
        __syncthreads();
    }
#pragma unroll
    for (int mt = 0; mt < MT; mt++) {
        int rbase = bm + wm * (16 * MT) + mt * 16 + lq * 4;
#pragma unroll
        for (int nt = 0; nt < NTW; nt++) {
            int col = wn * (16 * NTW) + nt * 16 + lm;
#pragma unroll
            for (int i = 0; i < 4; i++) {
                int rl = rbase + i;
                if (rl < rows && col < dout) {
                    float v = acc[mt][nt][i] + bias[col];
                    if (RELU) v = fmaxf(v, 0.f);
                    if (FINAL)
                        ((float*)outp)[(size_t)(r0 + rl) * NCLS + col] = v;
                    else
                        ((__hip_bfloat16*)outp)[(size_t)(r0 + rl) * DFEAT + col] =
                            __float2bfloat16(v);
                }
            }
        }
    }
}

extern "C" void kernel_launch(void* const* d_in, const int* in_sizes, int n_in,
                              void* d_out, int out_size, void* d_ws, size_t ws_size,
                              hipStream_t stream)
{
    const float* x  = (const float*)d_in[0];
    const int* esrc = (const int*)d_in[1];
    const int* edst = (const int*)d_in[2];
    const int* etyp = (const int*)d_in[3];
    const float* basesA[3] = {(const float*)d_in[4], (const float*)d_in[8], (const float*)d_in[12]};
    const float* compA[3]  = {(const float*)d_in[5], (const float*)d_in[9], (const float*)d_in[13]};
    const float* rootA[3]  = {(const float*)d_in[6], (const float*)d_in[10], (const float*)d_in[14]};
    const float* biasA[3]  = {(const float*)d_in[7], (const float*)d_in[11], (const float*)d_in[15]};

    size_t off = 0;
    char* base = (char*)d_ws;
    auto carve = [&](size_t bytes) -> void* {
        void* r = base + off;
        off += (bytes + 255) & ~(size_t)255;
        return r;
    };
    __hip_bfloat16* xb = (__hip_bfloat16*)carve((size_t)NNODES * DFEAT * 2);
    __hip_bfloat16* h1 = (__hip_bfloat16*)carve((size_t)NNODES * DFEAT * 2);
    __hip_bfloat16* WT = (__hip_bfloat16*)carve((size_t)128 * KTOT * 2);
    unsigned* ell  = (unsigned*)carve((size_t)NNODES * MAXDEG * 4);
    unsigned* degD = (unsigned*)carve((size_t)NNODES * 4);
    short* q8  = (short*)carve((size_t)NNODES * 64 * 2);
    float* qsc = (float*)carve((size_t)NNODES * 4);
    __hip_bfloat16* h2 = xb;   // xb dead after layer 1 -> alias

    if (ws_size <= off) return;
    size_t arows = (ws_size - off) / ((size_t)KTOT * 2);
    if (arows > 100096) arows = 100096;
    int chunk = (int)(arows & ~(size_t)127);
    if (chunk < 128) return;
    __hip_bfloat16* A = (__hip_bfloat16*)(base + off);

    hipMemsetAsync(degD, 0, (size_t)NNODES * 4, stream);
    k_convert<<<(NNODES * DFEAT + 255) / 256, 256, 0, stream>>>(x, xb, NNODES * DFEAT);
    k_build<<<(NEDGES + 255) / 256, 256, 0, stream>>>(esrc, edst, etyp, degD, ell);

    const __hip_bfloat16* hin = xb;
    __hip_bfloat16* houts[2] = {h1, h2};
    for (int l = 0; l < 3; l++) {
        int dout = (l == 2) ? NCLS : DFEAT;
        int npad = (l == 2) ? 64 : 128;
        k_quant<<<(NNODES + 3) / 4, 256, 0, stream>>>(hin, q8, qsc, NNODES);
        k_w<<<(npad * KTOT + 255) / 256, 256, 0, stream>>>(basesA[l], rootA[l], WT, dout, npad);
        for (int r0 = 0; r0 < NNODES; r0 += chunk) {
            int rows = NNODES - r0; if (rows > chunk) rows = chunk;
            k_agg<<<(rows + 3) / 4, 256, 0, stream>>>(q8, qsc, hin, ell, degD, compA[l], A, r0, rows);
            int gm = (rows + 127) / 128;
            if (l < 2)
                k_gemm<128, true, false><<<gm, 256, 0, stream>>>(A, WT, biasA[l], houts[l], r0, rows, dout);
            else
                k_gemm<64, false, true><<<gm, 256, 0, stream>>>(A, WT, biasA[l], d_out, r0, rows, dout);
        }
        if (l < 2) hin = houts[l];
    }
}